// Round 5
// baseline (443.433 us; speedup 1.0000x reference)
//
#include <hip/hip_runtime.h>
#include <hip/hip_bf16.h>

// SelfAttention B=2,N=4096,E=512,H=8,D=64 — Round 5:
// - attn split-K=4 (partials are plain sums: no max-tracking), KT=64 tiles,
//   LDS 26.25KB -> 6 blocks/CU, grid 2048: occupancy 8 -> 24 waves/CU.
// - bf16 O-partials + fp32 l-partials, merge kernel normalizes.
// - ws buffer sharing: xb/Ab, Opart/Pb (total ~99MB).

#define ROWS 8192
#define EMB  512
#define SEQ  4096
#define HEADS 8
#define HD   64
#define SPLIT 4
#define QSCALE 0.18033688011112042f   // 0.125 * log2(e)

typedef __attribute__((ext_vector_type(8))) short bf16x8;
typedef __attribute__((ext_vector_type(4))) float f32x4;

__device__ __forceinline__ float bf16_to_f(unsigned short u) {
    union { unsigned int i; float f; } v; v.i = ((unsigned int)u) << 16; return v.f;
}
__device__ __forceinline__ unsigned short f_to_bf16(float f) {
    union { __hip_bfloat16 h; unsigned short u; } v; v.h = __float2bfloat16(f); return v.u;
}
__device__ __forceinline__ unsigned short f_to_bf16_trunc(float f) {
    return (unsigned short)(__float_as_uint(f) >> 16);
}
__device__ __forceinline__ void load_lds16(const void* g, void* l) {
    __builtin_amdgcn_global_load_lds(
        (const __attribute__((address_space(1))) void*)g,
        (__attribute__((address_space(3))) void*)l, 16, 0, 0);
}

// ---- dtype detection (fp32 buffers: random halfwords -> wild exponents)
__global__ void detect_kernel(const void* x, int* flag) {
    const unsigned short* p = (const unsigned short*)x;
    int t = threadIdx.x;
    int cnt = 0;
    for (int i = 0; i < 4; ++i) {
        unsigned short u = p[t * 4 + i];
        int e = (u >> 7) & 0xFF;
        if (e >= 140) cnt++;
    }
    for (int off = 32; off > 0; off >>= 1) cnt += __shfl_down(cnt, off, 64);
    if (t == 0) *flag = (cnt > 16) ? 1 : 0;   // 1 = fp32, 0 = bf16
}

// ---- only needed when input fp32: x -> x_f (fp32 copy) + xb (bf16)
__global__ __launch_bounds__(256) void conv_x_kernel(const void* __restrict__ x,
        float* __restrict__ xf, unsigned short* __restrict__ xb, const int* __restrict__ flag) {
    if (*flag == 0) return;
    int i = (blockIdx.x * 256 + threadIdx.x) * 4;
    float4 v = *(const float4*)((const float*)x + i);
    *(float4*)(xf + i) = v;
    ushort4 u = { f_to_bf16(v.x), f_to_bf16(v.y), f_to_bf16(v.z), f_to_bf16(v.w) };
    *(ushort4*)(xb + i) = u;
}

// ---- weights [K][N] -> Wt bf16 [mat*512 + n][k]
__global__ __launch_bounds__(256) void conv_wt_kernel(
        const void* W0, const void* W1, const void* W2, const void* W3,
        unsigned short* __restrict__ Wt, const int* __restrict__ flag) {
    __shared__ float T[64][65];
    int tid = threadIdx.x;
    int kt = blockIdx.x, nt = blockIdx.y, mat = blockIdx.z;
    const void* src = (mat == 0) ? W0 : (mat == 1) ? W1 : (mat == 2) ? W2 : W3;
    int fp32 = *flag;
    for (int ii = 0; ii < 4; ++ii) {
        int idx = tid + ii * 256;
        int i = idx >> 4, j = (idx & 15) * 4;
        size_t g = (size_t)(kt * 64 + i) * 512 + nt * 64 + j;
        if (fp32) {
            float4 v = *(const float4*)((const float*)src + g);
            T[i][j] = v.x; T[i][j+1] = v.y; T[i][j+2] = v.z; T[i][j+3] = v.w;
        } else {
            ushort4 u = *(const ushort4*)((const unsigned short*)src + g);
            T[i][j] = bf16_to_f(u.x); T[i][j+1] = bf16_to_f(u.y);
            T[i][j+2] = bf16_to_f(u.z); T[i][j+3] = bf16_to_f(u.w);
        }
    }
    __syncthreads();
    for (int ii = 0; ii < 2; ++ii) {
        int idx = tid + ii * 256;
        int j = idx >> 3, ch = idx & 7;
        unsigned short pk[8];
        for (int t = 0; t < 8; ++t) pk[t] = f_to_bf16(T[ch * 8 + t][j]);
        *(bf16x8*)&Wt[(size_t)(mat * 512 + nt * 64 + j) * 512 + kt * 64 + ch * 8] = *(bf16x8*)pk;
    }
}

// ---- 6 small vectors -> bias_all fp32 [6][512]: bq,bk,bv,bo,gamma,beta
__global__ __launch_bounds__(256) void conv_small_kernel(
        const void* b0, const void* b1, const void* b2, const void* b3,
        const void* b4, const void* b5, float* __restrict__ dst, const int* __restrict__ flag) {
    int idx = blockIdx.x * 256 + threadIdx.x;
    int mat = idx >> 9, off = idx & 511;
    const void* src = (mat == 0) ? b0 : (mat == 1) ? b1 : (mat == 2) ? b2 :
                      (mat == 3) ? b3 : (mat == 4) ? b4 : b5;
    float v;
    if (*flag) v = ((const float*)src)[off];
    else       v = bf16_to_f(((const unsigned short*)src)[off]);
    dst[idx] = v;
}

// ---- MFMA GEMM: C = A * Bt^T + bias, 128x128x64 tiles. A chosen per flag.
template <typename OutT>
__global__ __launch_bounds__(256) void gemm_mfma_kernel(
        const unsigned short* __restrict__ A_conv, const unsigned short* __restrict__ A_raw,
        const int* __restrict__ flag,
        const unsigned short* __restrict__ Bt,
        const float* __restrict__ bias, OutT* __restrict__ C, int ldc, int scale_cols) {
    __shared__ unsigned short At[128 * 64];
    __shared__ unsigned short Bs[128 * 64];
    const unsigned short* A = (*flag) ? A_conv : A_raw;
    int tid = threadIdx.x;
    int wave = tid >> 6, lane = tid & 63;
    int l15 = lane & 15, quad = lane >> 4;
    int m0 = blockIdx.y * 128, n0 = blockIdx.x * 128;
    int wm = (wave & 1) * 64, wn = (wave >> 1) * 64;

    int rt = wave * 32 + (lane >> 3);
    int ch = (lane & 7) ^ ((lane >> 3) & 7);
    const unsigned short* ag = A  + (size_t)(m0 + rt) * 512 + ch * 8;
    const unsigned short* bg = Bt + (size_t)(n0 + rt) * 512 + ch * 8;

    f32x4 acc[4][4];
    for (int i = 0; i < 4; ++i) for (int j = 0; j < 4; ++j) acc[i][j] = (f32x4){0.f,0.f,0.f,0.f};

    for (int k0 = 0; k0 < 512; k0 += 64) {
        __syncthreads();
        #pragma unroll
        for (int j = 0; j < 4; ++j) {
            load_lds16(ag + (size_t)(j * 8) * 512 + k0, &At[(wave * 32 + j * 8) * 64]);
            load_lds16(bg + (size_t)(j * 8) * 512 + k0, &Bs[(wave * 32 + j * 8) * 64]);
        }
        __syncthreads();
        #pragma unroll
        for (int ks = 0; ks < 2; ++ks) {
            bf16x8 a[4], b[4];
            #pragma unroll
            for (int f = 0; f < 4; ++f) {
                int pc = ((ks * 4 + quad) ^ (l15 & 7)) * 8;
                a[f] = *(const bf16x8*)&At[(wm + f * 16 + l15) * 64 + pc];
                b[f] = *(const bf16x8*)&Bs[(wn + f * 16 + l15) * 64 + pc];
            }
            #pragma unroll
            for (int fm = 0; fm < 4; ++fm)
                #pragma unroll
                for (int fn = 0; fn < 4; ++fn)
                    acc[fm][fn] = __builtin_amdgcn_mfma_f32_16x16x32_bf16(a[fm], b[fn], acc[fm][fn], 0, 0, 0);
        }
    }
    #pragma unroll
    for (int fm = 0; fm < 4; ++fm) {
        #pragma unroll
        for (int fn = 0; fn < 4; ++fn) {
            int col = n0 + wn + fn * 16 + l15;
            float bia = bias[col];
            float sc = (col < scale_cols) ? QSCALE : 1.f;
            #pragma unroll
            for (int r = 0; r < 4; ++r) {
                int row = m0 + wm + fm * 16 + quad * 4 + r;
                float v = (acc[fm][fn][r] + bia) * sc;
                if constexpr (sizeof(OutT) == 2) C[(size_t)row * ldc + col] = (OutT)f_to_bf16(v);
                else                             C[(size_t)row * ldc + col] = v;
            }
        }
    }
}

// ---- V slice of QKV (bf16, cols 1024..1535) -> Vt [bh][d][seq] bf16
__global__ __launch_bounds__(256) void transpose_v_kernel(
        const unsigned short* __restrict__ QKV, unsigned short* __restrict__ Vt) {
    __shared__ unsigned short T[64][72];
    int tid = threadIdx.x;
    int nt = blockIdx.x, h = blockIdx.y, b = blockIdx.z;
    for (int ii = 0; ii < 2; ++ii) {
        int idx = tid + ii * 256;
        int n = idx >> 3, ch = idx & 7;
        *(bf16x8*)&T[n][ch * 8] =
            *(const bf16x8*)&QKV[(size_t)(b * SEQ + nt * 64 + n) * 1536 + 1024 + h * 64 + ch * 8];
    }
    __syncthreads();
    int bh = b * HEADS + h;
    for (int ii = 0; ii < 2; ++ii) {
        int idx = tid + ii * 256;
        int d = idx >> 3, ch = idx & 7;
        unsigned short pk[8];
        for (int t = 0; t < 8; ++t) pk[t] = T[ch * 8 + t][d];
        *(bf16x8*)&Vt[(size_t)(bh * 64 + d) * SEQ + nt * 64 + ch * 8] = *(bf16x8*)pk;
    }
}

// ---- MFMA flash attention, split-K: 4 waves x 32 q (block=128q), KT=64,
// blockIdx.z = b*SPLIT + s; each block sweeps k in [s*1024, (s+1)*1024).
// Writes unnormalized bf16 O-partials + fp32 l-partials.
__global__ __launch_bounds__(256, 6) void attn_kernel(
        const unsigned short* __restrict__ QKV, const unsigned short* __restrict__ Vt,
        unsigned short* __restrict__ Opart, float* __restrict__ Lpart) {
    __shared__ unsigned short Ks[64 * 64];       // [krow][d] xor-swizzled chunks
    __shared__ unsigned short Vs[64 * 64];       // [d][krow] xor-swizzled chunks
    __shared__ unsigned short Ps[4][32][40];     // per-wave P [q][kcol 0..31]
    int tid = threadIdx.x;
    int wave = tid >> 6, lane = tid & 63;
    int l15 = lane & 15, quad = lane >> 4;
    int key = l15 & 7;
    int qt = blockIdx.x, h = blockIdx.y;
    int b = blockIdx.z >> 2, s = blockIdx.z & 3;
    int bh = b * HEADS + h;
    int k0 = s * (SEQ / SPLIT);
    size_t qrow0 = (size_t)b * SEQ + qt * 128 + wave * 32;

    bf16x8 aq[2][2];
    #pragma unroll
    for (int t = 0; t < 2; ++t) {
        const unsigned short* qp = &QKV[(qrow0 + t * 16 + l15) * 1536 + h * 64];
        aq[t][0] = *(const bf16x8*)&qp[quad * 8];
        aq[t][1] = *(const bf16x8*)&qp[32 + quad * 8];
    }

    f32x4 o[2][4];
    #pragma unroll
    for (int t = 0; t < 2; ++t)
        #pragma unroll
        for (int db = 0; db < 4; ++db) o[t][db] = (f32x4){0.f,0.f,0.f,0.f};
    float lp[2][4] = {{0.f,0.f,0.f,0.f},{0.f,0.f,0.f,0.f}};

    int ldr = lane >> 3;                         // 0..7 staging row-in-8
    int kch = (lane & 7) ^ (ldr & 7);
    const unsigned short* kg =
        &QKV[((size_t)b * SEQ + k0 + wave * 16 + ldr) * 1536 + 512 + h * 64 + kch * 8];
    const unsigned short* vg =
        &Vt[((size_t)bh * 64 + wave * 16 + ldr) * SEQ + k0 + kch * 8];

    for (int kt = 0; kt < SEQ / SPLIT / 64; ++kt) {
        __syncthreads();
        #pragma unroll
        for (int j = 0; j < 2; ++j) {
            load_lds16(kg + (size_t)(kt * 64 + j * 8) * 1536, &Ks[(wave * 16 + j * 8) * 64]);
            load_lds16(vg + (size_t)(j * 8) * SEQ + kt * 64, &Vs[(wave * 16 + j * 8) * 64]);
        }
        __syncthreads();

        #pragma unroll
        for (int ks = 0; ks < 2; ++ks) {
            #pragma unroll
            for (int nn = 0; nn < 2; ++nn) {
                int nb = ks * 2 + nn;
                int row = (nb * 16 + l15) * 64;
                bf16x8 bk0 = *(const bf16x8*)&Ks[row + ((0 + quad) ^ key) * 8];
                bf16x8 bk1 = *(const bf16x8*)&Ks[row + ((4 + quad) ^ key) * 8];
                #pragma unroll
                for (int t = 0; t < 2; ++t) {
                    f32x4 z = {0.f, 0.f, 0.f, 0.f};
                    z = __builtin_amdgcn_mfma_f32_16x16x32_bf16(aq[t][0], bk0, z, 0, 0, 0);
                    z = __builtin_amdgcn_mfma_f32_16x16x32_bf16(aq[t][1], bk1, z, 0, 0, 0);
                    #pragma unroll
                    for (int r = 0; r < 4; ++r) {
                        float p = __builtin_amdgcn_exp2f(z[r]);
                        lp[t][r] += p;
                        Ps[wave][t * 16 + quad * 4 + r][nn * 16 + l15] = f_to_bf16_trunc(p);
                    }
                }
            }
            asm volatile("s_waitcnt lgkmcnt(0)" ::: "memory");
            bf16x8 ap0 = *(const bf16x8*)&Ps[wave][l15][quad * 8];
            bf16x8 ap1 = *(const bf16x8*)&Ps[wave][16 + l15][quad * 8];
            #pragma unroll
            for (int db = 0; db < 4; ++db) {
                bf16x8 bv = *(const bf16x8*)&Vs[(db * 16 + l15) * 64 + ((ks * 4 + quad) ^ key) * 8];
                o[0][db] = __builtin_amdgcn_mfma_f32_16x16x32_bf16(ap0, bv, o[0][db], 0, 0, 0);
                o[1][db] = __builtin_amdgcn_mfma_f32_16x16x32_bf16(ap1, bv, o[1][db], 0, 0, 0);
            }
        }
    }
    #pragma unroll
    for (int t = 0; t < 2; ++t)
        #pragma unroll
        for (int r = 0; r < 4; ++r) {
            float sum = lp[t][r];
            #pragma unroll
            for (int off = 1; off < 16; off <<= 1) sum += __shfl_xor(sum, off, 64);
            size_t row = qrow0 + t * 16 + quad * 4 + r;
            if (l15 == 0) Lpart[((size_t)s * ROWS + row) * 8 + h] = sum;
            #pragma unroll
            for (int db = 0; db < 4; ++db)
                Opart[((size_t)s * ROWS + row) * EMB + h * 64 + db * 16 + l15] =
                    f_to_bf16(o[t][db][r]);
        }
}

// ---- merge split-K partials: Ab = (sum_s O_s) / (sum_s l_s), bf16
__global__ __launch_bounds__(256) void merge_kernel(
        const unsigned short* __restrict__ Opart, const float* __restrict__ Lpart,
        unsigned short* __restrict__ Ab) {
    int idx4 = (blockIdx.x * 256 + threadIdx.x) * 4;
    int row = idx4 >> 9;
    int h = (idx4 & 511) >> 6;
    float l = 0.f;
    float acc[4] = {0.f, 0.f, 0.f, 0.f};
    #pragma unroll
    for (int s = 0; s < SPLIT; ++s) {
        l += Lpart[((size_t)s * ROWS + row) * 8 + h];
        ushort4 u = *(const ushort4*)&Opart[(size_t)s * ROWS * EMB + idx4];
        acc[0] += bf16_to_f(u.x); acc[1] += bf16_to_f(u.y);
        acc[2] += bf16_to_f(u.z); acc[3] += bf16_to_f(u.w);
    }
    float inv = 1.f / l;
    ushort4 out = { f_to_bf16(acc[0] * inv), f_to_bf16(acc[1] * inv),
                    f_to_bf16(acc[2] * inv), f_to_bf16(acc[3] * inv) };
    *(ushort4*)&Ab[idx4] = out;
}

// ---- y = x + P; LayerNorm -> out. 4 rows per block (1 wave each).
__global__ __launch_bounds__(256) void ln_kernel(
        const float* __restrict__ xf, const unsigned short* __restrict__ xraw,
        const unsigned short* __restrict__ P,
        const float* __restrict__ gamma, const float* __restrict__ beta,
        void* __restrict__ out, const int* __restrict__ flag) {
    int row = blockIdx.x * 4 + (threadIdx.x >> 6);
    int t = threadIdx.x & 63;
    int fp32 = *flag;
    float v[8];
    float s = 0.f, ss = 0.f;
    const unsigned short* pp = &P[(size_t)row * EMB + t * 8];
    ushort4 p0 = *(const ushort4*)&pp[0];
    ushort4 p1 = *(const ushort4*)&pp[4];
    float pv[8] = { bf16_to_f(p0.x), bf16_to_f(p0.y), bf16_to_f(p0.z), bf16_to_f(p0.w),
                    bf16_to_f(p1.x), bf16_to_f(p1.y), bf16_to_f(p1.z), bf16_to_f(p1.w) };
    if (fp32) {
        const float* xp = &xf[(size_t)row * EMB + t * 8];
        for (int i = 0; i < 8; i += 4) {
            float4 x4 = *(const float4*)&xp[i];
            v[i] = x4.x + pv[i]; v[i+1] = x4.y + pv[i+1];
            v[i+2] = x4.z + pv[i+2]; v[i+3] = x4.w + pv[i+3];
        }
    } else {
        const unsigned short* xp = &xraw[(size_t)row * EMB + t * 8];
        ushort4 x0 = *(const ushort4*)&xp[0];
        ushort4 x1 = *(const ushort4*)&xp[4];
        v[0] = bf16_to_f(x0.x) + pv[0]; v[1] = bf16_to_f(x0.y) + pv[1];
        v[2] = bf16_to_f(x0.z) + pv[2]; v[3] = bf16_to_f(x0.w) + pv[3];
        v[4] = bf16_to_f(x1.x) + pv[4]; v[5] = bf16_to_f(x1.y) + pv[5];
        v[6] = bf16_to_f(x1.z) + pv[6]; v[7] = bf16_to_f(x1.w) + pv[7];
    }
    for (int i = 0; i < 8; ++i) { s += v[i]; ss += v[i] * v[i]; }
    for (int off = 32; off > 0; off >>= 1) {
        s  += __shfl_xor(s, off, 64);
        ss += __shfl_xor(ss, off, 64);
    }
    float mu = s * (1.f / 512.f);
    float var = ss * (1.f / 512.f) - mu * mu;
    float rs = rsqrtf(var + 1e-5f);
    for (int i = 0; i < 8; ++i) {
        int col = t * 8 + i;
        float y = (v[i] - mu) * rs * gamma[col] + beta[col];
        if (fp32) ((float*)out)[(size_t)row * EMB + col] = y;
        else      ((__hip_bfloat16*)out)[(size_t)row * EMB + col] = __float2bfloat16(y);
    }
}

extern "C" void kernel_launch(void* const* d_in, const int* in_sizes, int n_in,
                              void* d_out, int out_size, void* d_ws, size_t ws_size,
                              hipStream_t stream) {
    char* ws = (char*)d_ws;
    int* flag = (int*)ws;
    char* p = ws + 256;
    float* x_f  = (float*)p;           p += (size_t)ROWS * EMB * 4;          // 16MB
    float* bias_all = (float*)p;       p += 6 * 512 * 4;
    unsigned short* Wt   = (unsigned short*)p; p += (size_t)2048 * 512 * 2;  // 2MB
    unsigned short* QKVb = (unsigned short*)p; p += (size_t)ROWS * 1536 * 2; // 24MB
    unsigned short* Vt   = (unsigned short*)p; p += (size_t)16 * HD * SEQ * 2; // 16MB
    // shared region A: xb (conv_x -> QKV gemm) then Ab (merge -> O-proj)
    unsigned short* xb = (unsigned short*)p;
    unsigned short* Ab = (unsigned short*)p;   p += (size_t)ROWS * EMB * 2;  // 8MB
    // shared region B: Opart (attn -> merge) then Pb (O-proj -> ln)
    unsigned short* Opart = (unsigned short*)p;
    unsigned short* Pb    = (unsigned short*)p; p += (size_t)SPLIT * ROWS * EMB * 2; // 32MB
    float* Lpart = (float*)p;          p += (size_t)SPLIT * ROWS * 8 * 4;    // 1MB

    detect_kernel<<<1, 64, 0, stream>>>(d_in[0], flag);

    conv_x_kernel<<<ROWS * EMB / 1024, 256, 0, stream>>>(d_in[0], x_f, xb, flag);
    conv_wt_kernel<<<dim3(8, 8, 4), 256, 0, stream>>>(d_in[1], d_in[3], d_in[5], d_in[7], Wt, flag);
    conv_small_kernel<<<12, 256, 0, stream>>>(d_in[2], d_in[4], d_in[6], d_in[8], d_in[9], d_in[10],
                                              bias_all, flag);

    // fused QKV: N=1536, Q cols (<512) pre-scaled by QSCALE
    gemm_mfma_kernel<unsigned short><<<dim3(12, 64), 256, 0, stream>>>(
        xb, (const unsigned short*)d_in[0], flag, Wt, bias_all, QKVb, 1536, 512);

    transpose_v_kernel<<<dim3(SEQ / 64, HEADS, 2), 256, 0, stream>>>(QKVb, Vt);

    attn_kernel<<<dim3(SEQ / 128, HEADS, 2 * SPLIT), 256, 0, stream>>>(QKVb, Vt, Opart, Lpart);

    merge_kernel<<<ROWS * EMB / 1024, 256, 0, stream>>>(Opart, Lpart, Ab);

    // O-proj -> bf16
    gemm_mfma_kernel<unsigned short><<<dim3(4, 64), 256, 0, stream>>>(
        Ab, Ab, flag, Wt + (size_t)1536 * 512, bias_all + 1536, Pb, 512, 0);

    ln_kernel<<<ROWS / 4, 256, 0, stream>>>(x_f, (const unsigned short*)d_in[0], Pb,
                                            bias_all + 4 * 512, bias_all + 5 * 512, d_out, flag);
}

// Round 6
// 269.452 us; speedup vs baseline: 1.6457x; 1.6457x over previous
//
#include <hip/hip_runtime.h>
#include <hip/hip_bf16.h>

// SelfAttention B=2,N=4096,E=512,H=8,D=64 — Round 6:
// attn rewrite: S^T = K·Q^T trick (K loaded straight to VGPRs, no K LDS; P's C-layout
// aligns with PV A-fragment after ONE per-wave LDS round trip per 128-k tile).
// Block = 64 q x 4 waves; wave owns a 32-kcol quarter, partial O (64 VGPR) + l in regs,
// one cross-wave LDS reduction in the epilogue. No split-K (R5 showed L2 thrash).

#define ROWS 8192
#define EMB  512
#define SEQ  4096
#define HEADS 8
#define HD   64
#define QSCALE 0.18033688011112042f   // 0.125 * log2(e)

typedef __attribute__((ext_vector_type(8))) short bf16x8;
typedef __attribute__((ext_vector_type(4))) float f32x4;

__device__ __forceinline__ float bf16_to_f(unsigned short u) {
    union { unsigned int i; float f; } v; v.i = ((unsigned int)u) << 16; return v.f;
}
__device__ __forceinline__ unsigned short f_to_bf16(float f) {
    union { __hip_bfloat16 h; unsigned short u; } v; v.h = __float2bfloat16(f); return v.u;
}
__device__ __forceinline__ unsigned int pack_bf16_trunc(float a, float b) {
    return (__float_as_uint(a) >> 16) | (__float_as_uint(b) & 0xFFFF0000u);
}
__device__ __forceinline__ void load_lds16(const void* g, void* l) {
    __builtin_amdgcn_global_load_lds(
        (const __attribute__((address_space(1))) void*)g,
        (__attribute__((address_space(3))) void*)l, 16, 0, 0);
}

// ---- dtype detection (fp32 buffers: random halfwords -> wild exponents)
__global__ void detect_kernel(const void* x, int* flag) {
    const unsigned short* p = (const unsigned short*)x;
    int t = threadIdx.x;
    int cnt = 0;
    for (int i = 0; i < 4; ++i) {
        unsigned short u = p[t * 4 + i];
        int e = (u >> 7) & 0xFF;
        if (e >= 140) cnt++;
    }
    for (int off = 32; off > 0; off >>= 1) cnt += __shfl_down(cnt, off, 64);
    if (t == 0) *flag = (cnt > 16) ? 1 : 0;   // 1 = fp32, 0 = bf16
}

// ---- only needed when input fp32: x -> x_f (fp32 copy) + xb (bf16)
__global__ __launch_bounds__(256) void conv_x_kernel(const void* __restrict__ x,
        float* __restrict__ xf, unsigned short* __restrict__ xb, const int* __restrict__ flag) {
    if (*flag == 0) return;
    int i = (blockIdx.x * 256 + threadIdx.x) * 4;
    float4 v = *(const float4*)((const float*)x + i);
    *(float4*)(xf + i) = v;
    ushort4 u = { f_to_bf16(v.x), f_to_bf16(v.y), f_to_bf16(v.z), f_to_bf16(v.w) };
    *(ushort4*)(xb + i) = u;
}

// ---- weights [K][N] -> Wt bf16 [mat*512 + n][k]
__global__ __launch_bounds__(256) void conv_wt_kernel(
        const void* W0, const void* W1, const void* W2, const void* W3,
        unsigned short* __restrict__ Wt, const int* __restrict__ flag) {
    __shared__ float T[64][65];
    int tid = threadIdx.x;
    int kt = blockIdx.x, nt = blockIdx.y, mat = blockIdx.z;
    const void* src = (mat == 0) ? W0 : (mat == 1) ? W1 : (mat == 2) ? W2 : W3;
    int fp32 = *flag;
    for (int ii = 0; ii < 4; ++ii) {
        int idx = tid + ii * 256;
        int i = idx >> 4, j = (idx & 15) * 4;
        size_t g = (size_t)(kt * 64 + i) * 512 + nt * 64 + j;
        if (fp32) {
            float4 v = *(const float4*)((const float*)src + g);
            T[i][j] = v.x; T[i][j+1] = v.y; T[i][j+2] = v.z; T[i][j+3] = v.w;
        } else {
            ushort4 u = *(const ushort4*)((const unsigned short*)src + g);
            T[i][j] = bf16_to_f(u.x); T[i][j+1] = bf16_to_f(u.y);
            T[i][j+2] = bf16_to_f(u.z); T[i][j+3] = bf16_to_f(u.w);
        }
    }
    __syncthreads();
    for (int ii = 0; ii < 2; ++ii) {
        int idx = tid + ii * 256;
        int j = idx >> 3, ch = idx & 7;
        unsigned short pk[8];
        for (int t = 0; t < 8; ++t) pk[t] = f_to_bf16(T[ch * 8 + t][j]);
        *(bf16x8*)&Wt[(size_t)(mat * 512 + nt * 64 + j) * 512 + kt * 64 + ch * 8] = *(bf16x8*)pk;
    }
}

// ---- 6 small vectors -> bias_all fp32 [6][512]: bq,bk,bv,bo,gamma,beta
__global__ __launch_bounds__(256) void conv_small_kernel(
        const void* b0, const void* b1, const void* b2, const void* b3,
        const void* b4, const void* b5, float* __restrict__ dst, const int* __restrict__ flag) {
    int idx = blockIdx.x * 256 + threadIdx.x;
    int mat = idx >> 9, off = idx & 511;
    const void* src = (mat == 0) ? b0 : (mat == 1) ? b1 : (mat == 2) ? b2 :
                      (mat == 3) ? b3 : (mat == 4) ? b4 : b5;
    float v;
    if (*flag) v = ((const float*)src)[off];
    else       v = bf16_to_f(((const unsigned short*)src)[off]);
    dst[idx] = v;
}

// ---- MFMA GEMM: C = A * Bt^T + bias, 128x128x64 tiles. A chosen per flag.
template <typename OutT>
__global__ __launch_bounds__(256) void gemm_mfma_kernel(
        const unsigned short* __restrict__ A_conv, const unsigned short* __restrict__ A_raw,
        const int* __restrict__ flag,
        const unsigned short* __restrict__ Bt,
        const float* __restrict__ bias, OutT* __restrict__ C, int ldc, int scale_cols) {
    __shared__ unsigned short At[128 * 64];
    __shared__ unsigned short Bs[128 * 64];
    const unsigned short* A = (*flag) ? A_conv : A_raw;
    int tid = threadIdx.x;
    int wave = tid >> 6, lane = tid & 63;
    int l15 = lane & 15, quad = lane >> 4;
    int m0 = blockIdx.y * 128, n0 = blockIdx.x * 128;
    int wm = (wave & 1) * 64, wn = (wave >> 1) * 64;

    int rt = wave * 32 + (lane >> 3);
    int ch = (lane & 7) ^ ((lane >> 3) & 7);
    const unsigned short* ag = A  + (size_t)(m0 + rt) * 512 + ch * 8;
    const unsigned short* bg = Bt + (size_t)(n0 + rt) * 512 + ch * 8;

    f32x4 acc[4][4];
    for (int i = 0; i < 4; ++i) for (int j = 0; j < 4; ++j) acc[i][j] = (f32x4){0.f,0.f,0.f,0.f};

    for (int k0 = 0; k0 < 512; k0 += 64) {
        __syncthreads();
        #pragma unroll
        for (int j = 0; j < 4; ++j) {
            load_lds16(ag + (size_t)(j * 8) * 512 + k0, &At[(wave * 32 + j * 8) * 64]);
            load_lds16(bg + (size_t)(j * 8) * 512 + k0, &Bs[(wave * 32 + j * 8) * 64]);
        }
        __syncthreads();
        #pragma unroll
        for (int ks = 0; ks < 2; ++ks) {
            bf16x8 a[4], b[4];
            #pragma unroll
            for (int f = 0; f < 4; ++f) {
                int pc = ((ks * 4 + quad) ^ (l15 & 7)) * 8;
                a[f] = *(const bf16x8*)&At[(wm + f * 16 + l15) * 64 + pc];
                b[f] = *(const bf16x8*)&Bs[(wn + f * 16 + l15) * 64 + pc];
            }
            #pragma unroll
            for (int fm = 0; fm < 4; ++fm)
                #pragma unroll
                for (int fn = 0; fn < 4; ++fn)
                    acc[fm][fn] = __builtin_amdgcn_mfma_f32_16x16x32_bf16(a[fm], b[fn], acc[fm][fn], 0, 0, 0);
        }
    }
    #pragma unroll
    for (int fm = 0; fm < 4; ++fm) {
        #pragma unroll
        for (int fn = 0; fn < 4; ++fn) {
            int col = n0 + wn + fn * 16 + l15;
            float bia = bias[col];
            float sc = (col < scale_cols) ? QSCALE : 1.f;
            #pragma unroll
            for (int r = 0; r < 4; ++r) {
                int row = m0 + wm + fm * 16 + quad * 4 + r;
                float v = (acc[fm][fn][r] + bia) * sc;
                if constexpr (sizeof(OutT) == 2) C[(size_t)row * ldc + col] = (OutT)f_to_bf16(v);
                else                             C[(size_t)row * ldc + col] = v;
            }
        }
    }
}

// ---- V slice of QKV (bf16, cols 1024..1535) -> Vt [bh][d][seq] bf16
__global__ __launch_bounds__(256) void transpose_v_kernel(
        const unsigned short* __restrict__ QKV, unsigned short* __restrict__ Vt) {
    __shared__ unsigned short T[64][72];
    int tid = threadIdx.x;
    int nt = blockIdx.x, h = blockIdx.y, b = blockIdx.z;
    for (int ii = 0; ii < 2; ++ii) {
        int idx = tid + ii * 256;
        int n = idx >> 3, ch = idx & 7;
        *(bf16x8*)&T[n][ch * 8] =
            *(const bf16x8*)&QKV[(size_t)(b * SEQ + nt * 64 + n) * 1536 + 1024 + h * 64 + ch * 8];
    }
    __syncthreads();
    int bh = b * HEADS + h;
    for (int ii = 0; ii < 2; ++ii) {
        int idx = tid + ii * 256;
        int d = idx >> 3, ch = idx & 7;
        unsigned short pk[8];
        for (int t = 0; t < 8; ++t) pk[t] = T[ch * 8 + t][d];
        *(bf16x8*)&Vt[(size_t)(bh * 64 + d) * SEQ + nt * 64 + ch * 8] = *(bf16x8*)pk;
    }
}

// ---- MFMA flash attention, transposed-S. Block = 64 q x 4 waves; wave w owns
// kcols [w*32, w*32+32) of each 128-k tile, sweeps all of K. Partial O/l in regs,
// cross-wave reduction in epilogue. No max-tracking (Q pre-scaled to log2 domain).
__global__ __launch_bounds__(256, 3) void attn_kernel(
        const unsigned short* __restrict__ QKV, const unsigned short* __restrict__ Vt,
        unsigned short* __restrict__ Ab) {
    __shared__ __align__(16) unsigned char arena[16384 + 20480 + 1024];
    unsigned short* Vs = (unsigned short*)arena;              // [64 d][128 k] (chunk-swizzled)
    unsigned short* Ps = (unsigned short*)(arena + 16384);    // [4 w][64 q][40]
    float* Lred = (float*)(arena + 16384 + 20480);            // [4 w][64 q]
    float* Ored = (float*)arena;                              // epilogue [4 w][32 q][68]

    int tid = threadIdx.x;
    int w = tid >> 6, lane = tid & 63;
    int l15 = lane & 15, quad = lane >> 4;
    int qt = blockIdx.x, h = blockIdx.y, b = blockIdx.z;
    int bh = b * HEADS + h;
    size_t qrow0 = (size_t)b * SEQ + qt * 64;

    // Q fragments (B-operand): lane l15 -> q row, quad -> d chunk. Pre-scaled by QSCALE.
    bf16x8 aq[4][2];
    #pragma unroll
    for (int qg = 0; qg < 4; ++qg) {
        const unsigned short* qp = &QKV[(qrow0 + qg * 16 + l15) * 1536 + h * 64];
        aq[qg][0] = *(const bf16x8*)&qp[quad * 8];
        aq[qg][1] = *(const bf16x8*)&qp[32 + quad * 8];
    }
    f32x4 o[4][4];                 // [qg][db] partial O, this wave's kcol quarter
    #pragma unroll
    for (int qg = 0; qg < 4; ++qg)
        #pragma unroll
        for (int db = 0; db < 4; ++db) o[qg][db] = (f32x4){0.f, 0.f, 0.f, 0.f};
    float lp[4] = {0.f, 0.f, 0.f, 0.f};

    const unsigned short* kbase = &QKV[((size_t)b * SEQ) * 1536 + 512 + h * 64];
    unsigned short* PsW = Ps + w * 64 * 40;

    // V staging indices (per-inst j): rows w*16+j*4+(lane>>4), stored chunk lane&15
    int vrow_in = lane >> 4;          // 0..3
    int vch_st  = lane & 15;          // stored 16B chunk

    for (int kt = 0; kt < 32; ++kt) {
        __syncthreads();              // previous Vs reads complete
        #pragma unroll
        for (int j = 0; j < 4; ++j) {
            int d = w * 16 + j * 4 + vrow_in;
            int sc = vch_st ^ (d & 7);
            load_lds16(&Vt[((size_t)bh * 64 + d) * SEQ + kt * 128 + sc * 8],
                       &Vs[(w * 16 + j * 4) * 128]);
        }
        // K rows straight to registers (A-operand of S^T): lane l15 -> kcol row
        bf16x8 kn[2][2];
        #pragma unroll
        for (int nb = 0; nb < 2; ++nb) {
            const unsigned short* kr = kbase + (size_t)(kt * 128 + w * 32 + nb * 16 + l15) * 1536;
            kn[nb][0] = *(const bf16x8*)&kr[quad * 8];
            kn[nb][1] = *(const bf16x8*)&kr[32 + quad * 8];
        }
        // S^T = K Q^T ; exp2 fused ; packed P -> per-wave LDS (layout [q][kcol_local])
        #pragma unroll
        for (int nb = 0; nb < 2; ++nb) {
            #pragma unroll
            for (int qg = 0; qg < 4; ++qg) {
                f32x4 s = {0.f, 0.f, 0.f, 0.f};
                s = __builtin_amdgcn_mfma_f32_16x16x32_bf16(kn[nb][0], aq[qg][0], s, 0, 0, 0);
                s = __builtin_amdgcn_mfma_f32_16x16x32_bf16(kn[nb][1], aq[qg][1], s, 0, 0, 0);
                float p0 = __builtin_amdgcn_exp2f(s[0]);
                float p1 = __builtin_amdgcn_exp2f(s[1]);
                float p2 = __builtin_amdgcn_exp2f(s[2]);
                float p3 = __builtin_amdgcn_exp2f(s[3]);
                lp[qg] += (p0 + p1) + (p2 + p3);
                uint2 u = { pack_bf16_trunc(p0, p1), pack_bf16_trunc(p2, p3) };
                *(uint2*)&PsW[(qg * 16 + l15) * 40 + nb * 16 + quad * 4] = u;
            }
        }
        __syncthreads();              // Vs staged (vmcnt drained by barrier)
        // PV: A = P (K=32 over this wave's kcols), B = V^T slices
        bf16x8 ap[4];
        #pragma unroll
        for (int qg = 0; qg < 4; ++qg)
            ap[qg] = *(const bf16x8*)&PsW[(qg * 16 + l15) * 40 + quad * 8];
        #pragma unroll
        for (int db = 0; db < 4; ++db) {
            int d = db * 16 + l15;
            int st = (w * 4 + quad) ^ (l15 & 7);
            bf16x8 bv = *(const bf16x8*)&Vs[d * 128 + st * 8];
            #pragma unroll
            for (int qg = 0; qg < 4; ++qg)
                o[qg][db] = __builtin_amdgcn_mfma_f32_16x16x32_bf16(ap[qg], bv, o[qg][db], 0, 0, 0);
        }
    }

    // ---- epilogue: reduce l over quads, O/l over waves via LDS (aliases Vs/Ps)
    #pragma unroll
    for (int qg = 0; qg < 4; ++qg) {
        float v = lp[qg];
        v += __shfl_xor(v, 16, 64);
        v += __shfl_xor(v, 32, 64);
        if (quad == 0) Lred[w * 64 + qg * 16 + l15] = v;
    }
    __syncthreads();                  // all PV + Lred writes done before Ored overwrite
    float* OredW = Ored + w * 32 * 68;
    #pragma unroll
    for (int p = 0; p < 2; ++p) {
        #pragma unroll
        for (int qh = 0; qh < 2; ++qh) {
            int qg = p * 2 + qh;
            #pragma unroll
            for (int db = 0; db < 4; ++db)
                #pragma unroll
                for (int r = 0; r < 4; ++r)
                    OredW[(qh * 16 + quad * 4 + r) * 68 + db * 16 + l15] = o[qg][db][r];
        }
        __syncthreads();
        {
            int q_l = tid >> 3;       // 0..31
            int dg = (tid & 7) * 8;
            float acc[8] = {0.f,0.f,0.f,0.f,0.f,0.f,0.f,0.f};
            #pragma unroll
            for (int wr = 0; wr < 4; ++wr) {
                const float* src = Ored + wr * 32 * 68 + q_l * 68 + dg;
                float4 a = *(const float4*)&src[0];
                float4 c = *(const float4*)&src[4];
                acc[0] += a.x; acc[1] += a.y; acc[2] += a.z; acc[3] += a.w;
                acc[4] += c.x; acc[5] += c.y; acc[6] += c.z; acc[7] += c.w;
            }
            int q = p * 32 + q_l;
            float lt = Lred[q] + Lred[64 + q] + Lred[128 + q] + Lred[192 + q];
            float inv = 1.f / lt;
            unsigned short pk[8];
            #pragma unroll
            for (int i = 0; i < 8; ++i) pk[i] = f_to_bf16(acc[i] * inv);
            *(bf16x8*)&Ab[(qrow0 + q) * EMB + h * 64 + dg] = *(bf16x8*)pk;
        }
        __syncthreads();
    }
}

// ---- y = x + P; LayerNorm -> out. 4 rows per block (1 wave each).
__global__ __launch_bounds__(256) void ln_kernel(
        const float* __restrict__ xf, const unsigned short* __restrict__ xraw,
        const unsigned short* __restrict__ P,
        const float* __restrict__ gamma, const float* __restrict__ beta,
        void* __restrict__ out, const int* __restrict__ flag) {
    int row = blockIdx.x * 4 + (threadIdx.x >> 6);
    int t = threadIdx.x & 63;
    int fp32 = *flag;
    float v[8];
    float s = 0.f, ss = 0.f;
    const unsigned short* pp = &P[(size_t)row * EMB + t * 8];
    ushort4 p0 = *(const ushort4*)&pp[0];
    ushort4 p1 = *(const ushort4*)&pp[4];
    float pv[8] = { bf16_to_f(p0.x), bf16_to_f(p0.y), bf16_to_f(p0.z), bf16_to_f(p0.w),
                    bf16_to_f(p1.x), bf16_to_f(p1.y), bf16_to_f(p1.z), bf16_to_f(p1.w) };
    if (fp32) {
        const float* xp = &xf[(size_t)row * EMB + t * 8];
        for (int i = 0; i < 8; i += 4) {
            float4 x4 = *(const float4*)&xp[i];
            v[i] = x4.x + pv[i]; v[i+1] = x4.y + pv[i+1];
            v[i+2] = x4.z + pv[i+2]; v[i+3] = x4.w + pv[i+3];
        }
    } else {
        const unsigned short* xp = &xraw[(size_t)row * EMB + t * 8];
        ushort4 x0 = *(const ushort4*)&xp[0];
        ushort4 x1 = *(const ushort4*)&xp[4];
        v[0] = bf16_to_f(x0.x) + pv[0]; v[1] = bf16_to_f(x0.y) + pv[1];
        v[2] = bf16_to_f(x0.z) + pv[2]; v[3] = bf16_to_f(x0.w) + pv[3];
        v[4] = bf16_to_f(x1.x) + pv[4]; v[5] = bf16_to_f(x1.y) + pv[5];
        v[6] = bf16_to_f(x1.z) + pv[6]; v[7] = bf16_to_f(x1.w) + pv[7];
    }
    for (int i = 0; i < 8; ++i) { s += v[i]; ss += v[i] * v[i]; }
    for (int off = 32; off > 0; off >>= 1) {
        s  += __shfl_xor(s, off, 64);
        ss += __shfl_xor(ss, off, 64);
    }
    float mu = s * (1.f / 512.f);
    float var = ss * (1.f / 512.f) - mu * mu;
    float rs = rsqrtf(var + 1e-5f);
    for (int i = 0; i < 8; ++i) {
        int col = t * 8 + i;
        float y = (v[i] - mu) * rs * gamma[col] + beta[col];
        if (fp32) ((float*)out)[(size_t)row * EMB + col] = y;
        else      ((__hip_bfloat16*)out)[(size_t)row * EMB + col] = __float2bfloat16(y);
    }
}

extern "C" void kernel_launch(void* const* d_in, const int* in_sizes, int n_in,
                              void* d_out, int out_size, void* d_ws, size_t ws_size,
                              hipStream_t stream) {
    char* ws = (char*)d_ws;
    int* flag = (int*)ws;
    char* p = ws + 256;
    float* x_f  = (float*)p;           p += (size_t)ROWS * EMB * 4;          // 16MB
    float* bias_all = (float*)p;       p += 6 * 512 * 4;
    unsigned short* Wt   = (unsigned short*)p; p += (size_t)2048 * 512 * 2;  // 2MB
    unsigned short* QKVb = (unsigned short*)p; p += (size_t)ROWS * 1536 * 2; // 24MB
    unsigned short* Vt   = (unsigned short*)p; p += (size_t)16 * HD * SEQ * 2; // 16MB
    // shared region: xb (conv_x -> QKV gemm) then Ab (attn -> O-proj)
    unsigned short* xb = (unsigned short*)p;
    unsigned short* Ab = (unsigned short*)p;   p += (size_t)ROWS * EMB * 2;  // 8MB
    unsigned short* Pb = (unsigned short*)p;   p += (size_t)ROWS * EMB * 2;  // 8MB

    detect_kernel<<<1, 64, 0, stream>>>(d_in[0], flag);

    conv_x_kernel<<<ROWS * EMB / 1024, 256, 0, stream>>>(d_in[0], x_f, xb, flag);
    conv_wt_kernel<<<dim3(8, 8, 4), 256, 0, stream>>>(d_in[1], d_in[3], d_in[5], d_in[7], Wt, flag);
    conv_small_kernel<<<12, 256, 0, stream>>>(d_in[2], d_in[4], d_in[6], d_in[8], d_in[9], d_in[10],
                                              bias_all, flag);

    // fused QKV: N=1536, Q cols (<512) pre-scaled by QSCALE
    gemm_mfma_kernel<unsigned short><<<dim3(12, 64), 256, 0, stream>>>(
        xb, (const unsigned short*)d_in[0], flag, Wt, bias_all, QKVb, 1536, 512);

    transpose_v_kernel<<<dim3(SEQ / 64, HEADS, 2), 256, 0, stream>>>(QKVb, Vt);

    attn_kernel<<<dim3(SEQ / 64, HEADS, 2), 256, 0, stream>>>(QKVb, Vt, Ab);

    // O-proj -> bf16
    gemm_mfma_kernel<unsigned short><<<dim3(4, 64), 256, 0, stream>>>(
        Ab, Ab, flag, Wt + (size_t)1536 * 512, bias_all + 1536, Pb, 512, 0);

    ln_kernel<<<ROWS / 4, 256, 0, stream>>>(x_f, (const unsigned short*)d_in[0], Pb,
                                            bias_all + 4 * 512, bias_all + 5 * 512, d_out, flag);
}